// Round 12
// baseline (676.361 us; speedup 1.0000x reference)
//
#include <hip/hip_runtime.h>
#include <math.h>

// ---------------------------------------------------------------------------
// Encoder_50414326120900 — round 12:
//  (a) stride-2 LDS swizzle fixed: granule XOR alone can't help (16B granules
//      keep b64 starts ===0 mod 4 dw -> inherent 8-way). Add half-swap: swap
//      the two 8B halves by column parity ((col>>1)&1) -> lo-starts cover
//      odd dword-pairs too -> 4/bank (b64 floor).
//  (b) norm_relu passes deleted: loss23 normalizes S in-place (then losses),
//      convt_l1 normalizes A during staging (writes back), reads normalized S.
// Rest identical to round 11.
// ---------------------------------------------------------------------------

typedef __attribute__((ext_vector_type(8))) short short8v;
typedef __attribute__((ext_vector_type(4))) short short4v;
typedef __attribute__((ext_vector_type(4))) float f32x4;

__device__ __forceinline__ unsigned short f2bf(float f) {
  union { float f; unsigned u; } a; a.f = f;
  unsigned r = a.u + 0x7fffu + ((a.u >> 16) & 1u);
  return (unsigned short)(r >> 16);
}
__device__ __forceinline__ float bf2f(unsigned short h) {
  union { unsigned u; float f; } a; a.u = ((unsigned)h) << 16;
  return a.f;
}

__device__ __forceinline__ float wave_reduce(float v) {
#pragma unroll
  for (int off = 32; off; off >>= 1) v += __shfl_down(v, off, 64);
  return v;
}

// ---------------- merged weight reorder -------------------------------------
template <int CI, int CO>
__device__ __forceinline__ void reord1(const float* __restrict__ w,
                                       unsigned short* __restrict__ wr,
                                       int idx) {
  int e = idx & 7;
  int t = idx >> 3;
  int co = t % CO; t /= CO;
  int ci8 = t % (CI / 8);
  int kk = t / (CI / 8);
  int ci = ci8 * 8 + e;
  wr[idx] = f2bf(w[((size_t)co * CI + ci) * 9 + kk]);
}

__global__ __launch_bounds__(256) void wreord_all_k(
    const float* __restrict__ w2, const float* __restrict__ w3,
    const float* __restrict__ ws1, const float* __restrict__ ws2,
    unsigned short* __restrict__ w2r, unsigned short* __restrict__ w3r,
    unsigned short* __restrict__ ws1r, unsigned short* __restrict__ ws2r) {
  int idx = blockIdx.x * 256 + threadIdx.x;
  if (idx < 18432) reord1<32, 64>(w2, w2r, idx);
  else if (idx < 55296) reord1<64, 64>(w3, w3r, idx - 18432);
  else if (idx < 110592) reord1<32, 192>(ws1, ws1r, idx - 55296);
  else if (idx < 442368) reord1<192, 192>(ws2, ws2r, idx - 110592);
}

// ---------------- L0: 3->32 conv 3x3 s1, fp32 math, bf16 out + fused stats --
__global__ __launch_bounds__(256) void conv0_k(const float* __restrict__ in,
                                               const float* __restrict__ w,
                                               unsigned short* __restrict__ outB,
                                               double* __restrict__ part) {
  __shared__ __align__(16) float tile[3][34][36];
  const int b = blockIdx.x;
  const int co0 = blockIdx.y * 8;
  const int tid = threadIdx.x;
  const int row = tid >> 3, x0 = (tid & 7) * 4;
  const int wv = tid >> 6;

  float* tf = &tile[0][0][0];
  for (int i = tid; i < 918; i += 256)
    *(float4*)(tf + i * 4) = make_float4(0.f, 0.f, 0.f, 0.f);
  __syncthreads();
  for (int i = tid; i < 768; i += 256) {
    int x4 = i & 7, yy = (i >> 3) & 31, c = i >> 8;
    float4 v = *(const float4*)&in[(((size_t)b * 3 + c) * 32 + yy) * 32 + x4 * 4];
    float* dst = &tile[c][yy + 1][1 + x4 * 4];
    dst[0] = v.x; dst[1] = v.y; dst[2] = v.z; dst[3] = v.w;
  }
  __syncthreads();

  float acc[4][8];
#pragma unroll
  for (int p = 0; p < 4; ++p)
#pragma unroll
    for (int co = 0; co < 8; ++co) acc[p][co] = 0.f;

#pragma unroll
  for (int c = 0; c < 3; ++c)
#pragma unroll
    for (int ky = 0; ky < 3; ++ky) {
      const float* tr = &tile[c][row + ky][x0];
      float4 vlo = *(const float4*)tr;
      float2 vhi = *(const float2*)(tr + 4);
      float v[6] = {vlo.x, vlo.y, vlo.z, vlo.w, vhi.x, vhi.y};
#pragma unroll
      for (int kx = 0; kx < 3; ++kx)
#pragma unroll
        for (int co = 0; co < 8; ++co) {
          float wvv = w[((size_t)(co0 + co) * 3 + c) * 9 + ky * 3 + kx];
#pragma unroll
          for (int p = 0; p < 4; ++p)
            acc[p][co] = fmaf(v[p + kx], wvv, acc[p][co]);
        }
    }
#pragma unroll
  for (int p = 0; p < 4; ++p) {
    short8v o;
#pragma unroll
    for (int co = 0; co < 8; ++co) o[co] = (short)f2bf(acc[p][co]);
    *(short8v*)&outB[(((size_t)b * 32 + row) * 32 + x0 + p) * 32 + co0] = o;
  }

  float s8[8], q8[8];
#pragma unroll
  for (int co = 0; co < 8; ++co) {
    float s = 0.f, q = 0.f;
#pragma unroll
    for (int p = 0; p < 4; ++p) {
      float v = acc[p][co];
      s += v;
      q = fmaf(v, v, q);
    }
    s8[co] = wave_reduce(s);
    q8[co] = wave_reduce(q);
  }
  __syncthreads();
  float* sb = (float*)tile;
  if ((tid & 63) == 0) {
#pragma unroll
    for (int co = 0; co < 8; ++co) {
      sb[wv * 8 + co] = s8[co];
      sb[32 + wv * 8 + co] = q8[co];
    }
  }
  __syncthreads();
  if (tid < 8) {
    float S = 0.f, Q = 0.f;
#pragma unroll
    for (int k = 0; k < 4; ++k) {
      S += sb[k * 8 + tid];
      Q += sb[32 + k * 8 + tid];
    }
    size_t slot = ((size_t)(co0 + tid) * 1024 + b) * 2;
    part[slot] = (double)S;
    part[slot + 1] = (double)Q;
  }
}

// ---------------- LDS-staged MFMA GEMM-conv 3x3 (pad 1) + fused stats -------
// SWZ (stride-2): granule XOR (col&7) + HALF-SWAP by ((col>>1)&1) — the swap
// puts b64 lo-reads on odd dword-pairs too (granule XOR alone keeps starts
// ===0 mod 4 -> inherent 8-way; measured r11: conflicts unchanged).
template <int CI_T, int CI0, int CI, int CIP, int CO, int COB, int IHW,
          int OHW, int STRIDE, int ORPB, int WM, int WN, int CTM, int CTN,
          bool OUT_BF16T>
__global__ __launch_bounds__(512) void convgemm_k(
    const unsigned short* __restrict__ inT, const float* __restrict__ ss,
    const unsigned short* __restrict__ wr_w, float* __restrict__ outF,
    unsigned short* __restrict__ outB, double* __restrict__ part) {
  constexpr int IR = (ORPB - 1) * STRIDE + 3;
  constexpr int IW2 = IHW + 2;
  constexpr int NPX = ORPB * OHW;
  constexpr int NPIX = OHW * OHW;
  constexpr bool SWZ = (STRIDE == 2);
  static_assert(WM * WN == 8, "8 waves");
  static_assert(WN * CTN * 16 == NPX, "px tiling");
  static_assert(WM * CTM * 16 == COB, "co tiling");
  static_assert((IR * IW2 * CIP) % 4 == 0, "zero fill");
  static_assert(IR * IW2 * CIP * 2 >= 8 * CTM * 16 * 2 * 4, "stats overlay");
  static_assert(!SWZ || (CI / 8) % 8 == 0, "swizzle octet closure");
  __shared__ __align__(16) unsigned short st[IR * IW2 * CIP];

  const int b = blockIdx.x;
  const int oy0 = blockIdx.y * ORPB;
  const int co_base = blockIdx.z * COB;
  const int tid = threadIdx.x;
  const int w = tid >> 6, l = tid & 63;
  const int l16 = l & 15, g = l >> 4;
  const int wrow = w / WN, wcol = w % WN;

  {
    uint2 z = make_uint2(0u, 0u);
    uint2* stz = (uint2*)st;
    constexpr int NZ = IR * IW2 * CIP / 4;
    for (int i = tid; i < NZ; i += 512) stz[i] = z;
  }
  __syncthreads();

  {
    constexpr int CPP = CI / 8;
    constexpr int NCH = IR * IHW * CPP;
    const int r0in = oy0 * STRIDE - 1;
    for (int i = tid; i < NCH; i += 512) {
      int c8 = i % CPP;
      int xx = (i / CPP) % IHW;
      int ir = i / (CPP * IHW);
      int iy = r0in + ir;
      if ((unsigned)iy < (unsigned)IHW) {
        short8v raw = *(const short8v*)&inT[(((size_t)b * IHW + iy) * IHW + xx) *
                                            CI_T + CI0 + c8 * 8];
        f32x4 sc0 = *(const f32x4*)&ss[CI0 + c8 * 8];
        f32x4 sc1 = *(const f32x4*)&ss[CI0 + c8 * 8 + 4];
        f32x4 sh0 = *(const f32x4*)&ss[CI_T + CI0 + c8 * 8];
        f32x4 sh1 = *(const f32x4*)&ss[CI_T + CI0 + c8 * 8 + 4];
        short4v lo, hi;
#pragma unroll
        for (int e = 0; e < 4; ++e) {
          float f = bf2f((unsigned short)raw[e]);
          f = fmaxf(fmaf(f, sc0[e], sh0[e]), 0.f);
          lo[e] = (short)f2bf(f);
        }
#pragma unroll
        for (int e = 0; e < 4; ++e) {
          float f = bf2f((unsigned short)raw[e + 4]);
          f = fmaxf(fmaf(f, sc1[e], sh1[e]), 0.f);
          hi[e] = (short)f2bf(f);
        }
        int xcol = xx + 1;
        int gran = SWZ ? (c8 ^ (xcol & 7)) : c8;
        int pp = SWZ ? ((xcol >> 1) & 1) : 0;
        unsigned short* dst = &st[(ir * IW2 + xcol) * CIP + gran * 8];
        *(short4v*)(dst + 4 * pp) = lo;
        *(short4v*)(dst + 4 * (1 - pp)) = hi;
      }
    }
  }
  __syncthreads();

  int prow[CTN], pxx[CTN];
#pragma unroll
  for (int pn = 0; pn < CTN; ++pn) {
    int pxl = (wcol * CTN + pn) * 16 + l16;
    int ly = pxl / OHW, lx = pxl % OHW;
    prow[pn] = (ly * STRIDE * IW2 + lx * STRIDE) * CIP;
    pxx[pn] = lx * STRIDE;
  }
  const int co_off = co_base + wrow * CTM * 16 + l16;

  f32x4 acc[CTM][CTN];
#pragma unroll
  for (int cm = 0; cm < CTM; ++cm)
#pragma unroll
    for (int pn = 0; pn < CTN; ++pn) {
      f32x4 z = {0.f, 0.f, 0.f, 0.f};
      acc[cm][pn] = z;
    }

#pragma unroll 3
  for (int kk = 0; kk < 9; ++kk) {
    const int ky = kk / 3, kx = kk % 3;
    const int rowadd = (ky * IW2 + kx) * CIP;
#pragma unroll
    for (int cs = 0; cs < CI / 32; ++cs) {
      short8v bfr[CTN];
#pragma unroll
      for (int pn = 0; pn < CTN; ++pn) {
        int col = pxx[pn] + kx;
        int gran = cs * 4 + g;
        int pp = 0;
        if (SWZ) {
          gran ^= (col & 7);
          pp = (col >> 1) & 1;
        }
        const unsigned short* bp = &st[prow[pn] + rowadd + gran * 8];
        short4v lo = *(const short4v*)(bp + 4 * pp);
        short4v hi = *(const short4v*)(bp + 4 * (1 - pp));
        short8v v = {lo[0], lo[1], lo[2], lo[3], hi[0], hi[1], hi[2], hi[3]};
        bfr[pn] = v;
      }
      const unsigned short* wb =
          wr_w + ((size_t)(kk * (CI / 8) + cs * 4 + g) * CO + co_off) * 8;
      short8v afr[CTM];
#pragma unroll
      for (int cm = 0; cm < CTM; ++cm)
        afr[cm] = *(const short8v*)(wb + cm * 128);
#pragma unroll
      for (int cm = 0; cm < CTM; ++cm)
#pragma unroll
        for (int pn = 0; pn < CTN; ++pn)
          acc[cm][pn] = __builtin_amdgcn_mfma_f32_16x16x32_bf16(
              afr[cm], bfr[pn], acc[cm][pn], 0, 0, 0);
    }
  }

#pragma unroll
  for (int cm = 0; cm < CTM; ++cm)
#pragma unroll
    for (int pn = 0; pn < CTN; ++pn) {
      int pxl = (wcol * CTN + pn) * 16 + l16;
      size_t pxg = (size_t)oy0 * OHW + pxl;
      int co = co_base + (wrow * CTM + cm) * 16 + g * 4;
      if (OUT_BF16T) {
        unsigned d0 = (unsigned)f2bf(acc[cm][pn][0]) |
                      ((unsigned)f2bf(acc[cm][pn][1]) << 16);
        unsigned d1 = (unsigned)f2bf(acc[cm][pn][2]) |
                      ((unsigned)f2bf(acc[cm][pn][3]) << 16);
        unsigned* dst = (unsigned*)&outB[((size_t)b * NPIX + pxg) * CO + co];
        dst[0] = d0;
        dst[1] = d1;
      } else {
#pragma unroll
        for (int r = 0; r < 4; ++r)
          outF[((size_t)b * CO + co + r) * NPIX + pxg] = acc[cm][pn][r];
      }
    }

  float sst[CTM][4], qst[CTM][4];
#pragma unroll
  for (int cm = 0; cm < CTM; ++cm)
#pragma unroll
    for (int r = 0; r < 4; ++r) {
      float s = 0.f, q = 0.f;
#pragma unroll
      for (int pn = 0; pn < CTN; ++pn) {
        float v = acc[cm][pn][r];
        s += v;
        q = fmaf(v, v, q);
      }
#pragma unroll
      for (int mask = 1; mask < 16; mask <<= 1) {
        s += __shfl_xor(s, mask, 64);
        q += __shfl_xor(q, mask, 64);
      }
      sst[cm][r] = s;
      qst[cm][r] = q;
    }
  __syncthreads();
  float* sbuf = (float*)st;
  float* qbuf = sbuf + 8 * CTM * 16;
  if (l16 == 0) {
#pragma unroll
    for (int cm = 0; cm < CTM; ++cm)
#pragma unroll
      for (int r = 0; r < 4; ++r) {
        sbuf[((w * CTM + cm) * 4 + g) * 4 + r] = sst[cm][r];
        qbuf[((w * CTM + cm) * 4 + g) * 4 + r] = qst[cm][r];
      }
  }
  __syncthreads();
  if (tid < COB) {
    int wrow_t = tid / (CTM * 16);
    int rem = tid % (CTM * 16);
    float S = 0.f, Q = 0.f;
#pragma unroll
    for (int j = 0; j < WN; ++j) {
      int wvx = wrow_t * WN + j;
      S += sbuf[(wvx * CTM) * 16 + rem];
      Q += qbuf[(wvx * CTM) * 16 + rem];
    }
    const int blk = blockIdx.x * gridDim.y + blockIdx.y;
    const int nblk = 1024 * gridDim.y;
    size_t slot = ((size_t)(co_base + tid) * nblk + blk) * 2;
    part[slot] = (double)S;
    part[slot + 1] = (double)Q;
  }
}

// ---------------- BN scale/shift — parallel deterministic tree reduce -------
__global__ __launch_bounds__(256) void finalize_k(
    const double* __restrict__ part, int NB, const float* __restrict__ g,
    const float* __restrict__ bb, float* __restrict__ ss, int C, double invN) {
  __shared__ double sms[256], smq[256];
  const int c = blockIdx.x;
  const int t = threadIdx.x;
  double s = 0.0, q = 0.0;
  const double* base = part + (size_t)c * NB * 2;
  for (int i = t; i < NB; i += 256) {
    s += base[i * 2];
    q += base[i * 2 + 1];
  }
  sms[t] = s;
  smq[t] = q;
  __syncthreads();
  for (int st = 128; st; st >>= 1) {
    if (t < st) {
      sms[t] += sms[t + st];
      smq[t] += smq[t + st];
    }
    __syncthreads();
  }
  if (t == 0) {
    double mean = sms[0] * invN;
    double var = smq[0] * invN - mean * mean;
    float scale = g[c] * rsqrtf((float)var + 1e-5f);
    float shift = bb[c] - (float)mean * scale;
    ss[c] = scale;
    ss[C + c] = shift;
  }
}

// ---------------- L3: 1x1 conv from channel-last bf16 y3b + fused stats -----
__global__ __launch_bounds__(256) void conv1x1_k(
    const unsigned short* __restrict__ inT, const float* __restrict__ ss,
    const float* __restrict__ w, float* __restrict__ out,
    double* __restrict__ part) {
  __shared__ float sb1x[4][16], qb1x[4][16];
  const int b = blockIdx.x;
  const int co0 = blockIdx.y * 16;
  const int px = threadIdx.x;
  const int wv = threadIdx.x >> 6;
  float acc[16];
#pragma unroll
  for (int co = 0; co < 16; ++co) acc[co] = 0.f;
  const unsigned short* rowp = inT + ((size_t)b * 256 + px) * 64;
#pragma unroll
  for (int c8 = 0; c8 < 4; ++c8) {
    short8v raw = *(const short8v*)(rowp + c8 * 8);
#pragma unroll
    for (int e = 0; e < 8; ++e) {
      int c = c8 * 8 + e;
      float f = bf2f((unsigned short)raw[e]);
      f = fmaxf(fmaf(f, ss[c], ss[64 + c]), 0.f);
#pragma unroll
      for (int co = 0; co < 16; ++co)
        acc[co] = fmaf(f, w[(co0 + co) * 32 + c], acc[co]);
    }
  }
#pragma unroll
  for (int co = 0; co < 16; ++co)
    out[((size_t)b * 64 + co0 + co) * 256 + px] = acc[co];

#pragma unroll
  for (int co = 0; co < 16; ++co) {
    float s = wave_reduce(acc[co]);
    float q = wave_reduce(acc[co] * acc[co]);
    if ((threadIdx.x & 63) == 0) {
      sb1x[wv][co] = s;
      qb1x[wv][co] = q;
    }
  }
  __syncthreads();
  if (px < 16) {
    float S = 0.f, Q = 0.f;
#pragma unroll
    for (int k = 0; k < 4; ++k) {
      S += sb1x[k][px];
      Q += qb1x[k][px];
    }
    size_t slot = ((size_t)(co0 + px) * 1024 + b) * 2;
    part[slot] = (double)S;
    part[slot + 1] = (double)Q;
  }
}

// ---------------- convT (stride2,pad3) via MFMA + sigmoid-MSE ---------------
// A arrives RAW; normalized here with ssA (written back to d_out).
// S arrives NORMALIZED (loss23 ran first).
__global__ __launch_bounds__(256) void convt_l1_k(float* __restrict__ A,
                                                  const float* __restrict__ S,
                                                  const float* __restrict__ x,
                                                  const float* __restrict__ ssA,
                                                  double* __restrict__ l1p) {
  __shared__ unsigned short Ab[8][256][8];
  __shared__ unsigned short Sb[4][16][3][72];
  __shared__ float sbred[4];
  const int b = blockIdx.x, tid = threadIdx.x;
  const int w = tid >> 6, l = tid & 63;
  const int g = l >> 4, c = l & 15;
  const int pa = w >> 1, pb = w & 1;

  float* Ag = A + (size_t)b * 16384;
  for (int dp = 0; dp < 32; ++dp) {
    int d = dp * 2;
    float f0 = Ag[(size_t)d * 256 + tid];
    float f1 = Ag[(size_t)(d + 1) * 256 + tid];
    f0 = fmaxf(fmaf(f0, ssA[d], ssA[64 + d]), 0.f);
    f1 = fmaxf(fmaf(f1, ssA[d + 1], ssA[64 + d + 1]), 0.f);
    Ag[(size_t)d * 256 + tid] = f0;
    Ag[(size_t)(d + 1) * 256 + tid] = f1;
    unsigned lo = f2bf(f0);
    unsigned hi = f2bf(f1);
    *(unsigned*)&Ab[d >> 3][tid][d & 7] = lo | (hi << 16);
  }
  const float* Sg = S + (size_t)b * 12288;
  for (int i = tid; i < 12288; i += 256) {
    int cch = i >> 6;
    int tap = i & 63;
    int d = cch / 3, t = cch - 3 * d;
    int ky = tap >> 3, kx = tap & 7;
    int par = (((ky & 1) ^ 1) << 1) | ((kx & 1) ^ 1);
    Sb[par][(ky >> 1) * 4 + (kx >> 1)][t][d] = f2bf(Sg[i]);
  }
  __syncthreads();

  f32x4 acc[16];
#pragma unroll
  for (int nt = 0; nt < 16; ++nt) {
    f32x4 z = {0.f, 0.f, 0.f, 0.f};
    acc[nt] = z;
  }

  const int shy = 1 + pa, shx = 1 + pb;
  for (int s = 0; s < 32; ++s) {
    const int tap = s >> 1;
    const int m = tap >> 2, n = tap & 3;
    const int dh = s & 1;
    short8v afr = {0, 0, 0, 0, 0, 0, 0, 0};
    if (c < 3) afr = *(const short8v*)&Sb[w][tap][c][dh * 32 + g * 8];
    const int ix = c + shx - n;
    const bool xok = (unsigned)ix < 16u;
    const int dblk = dh * 4 + g;
#pragma unroll
    for (int nt = 0; nt < 16; ++nt) {
      int iy = nt + shy - m;
      if ((unsigned)iy >= 16u) continue;
      short8v bfr = {0, 0, 0, 0, 0, 0, 0, 0};
      if (xok) bfr = *(const short8v*)&Ab[dblk][iy * 16 + ix][0];
      acc[nt] = __builtin_amdgcn_mfma_f32_16x16x32_bf16(afr, bfr, acc[nt],
                                                        0, 0, 0);
    }
  }

  float loc = 0.f;
  if (g == 0) {
    const float* xg = x + (size_t)b * 3072;
#pragma unroll
    for (int nt = 0; nt < 16; ++nt) {
      int oy = 2 * nt + pa, ox = 2 * c + pb;
#pragma unroll
      for (int r = 0; r < 3; ++r) {
        float recon = 1.f / (1.f + expf(-acc[nt][r]));
        float img = 1.f / (1.f + expf(-xg[r * 1024 + oy * 32 + ox]));
        float dd = img - recon;
        loc = fmaf(dd, dd, loc);
      }
    }
  }
  loc = wave_reduce(loc);
  if (l == 0) sbred[w] = loc;
  __syncthreads();
  if (tid == 0)
    l1p[b] = (double)(sbred[0] + sbred[1] + sbred[2] + sbred[3]);
}

// ---------------- loss23: normalize S in-place + l2 + l3 --------------------
__global__ __launch_bounds__(256) void loss23_k(float* __restrict__ S,
                                                const float* __restrict__ ss,
                                                double* __restrict__ l2p,
                                                double* __restrict__ l3p) {
  __shared__ float ssl[384];
  __shared__ float sb1[4], sb2[4];
  for (int i = threadIdx.x; i < 384; i += 256) ssl[i] = ss[i];
  __syncthreads();
  int gid = blockIdx.x * 256 + threadIdx.x;
  int b = gid / 192;
  int r = gid - b * 192;
  int t = r >> 6, p = r & 63;
  float* base = S + ((size_t)b * 192 + t) * 64 + p;
  float v[64];
  float l2 = 0.f, m = -1e30f;
#pragma unroll
  for (int d = 0; d < 64; ++d) {
    float raw = base[(size_t)d * 192];
    int cch = d * 3 + t;
    float f = fmaxf(fmaf(raw, ssl[cch], ssl[192 + cch]), 0.f);
    v[d] = f;
    m = fmaxf(m, f);
    l2 += f;  // f >= 0, relu(f) == f
  }
#pragma unroll
  for (int d = 0; d < 64; ++d) base[(size_t)d * 192] = v[d];
  float Z = 0.f;
#pragma unroll
  for (int d = 0; d < 64; ++d) Z += expf(v[d] - m);
  float lZ = logf(Z);
  float l3 = 0.f;
#pragma unroll
  for (int d = 0; d < 64; ++d) {
    float lp = v[d] - m - lZ;
    l3 = fmaf(expf(lp), lp, l3);
  }
  l2 = wave_reduce(l2);
  l3 = wave_reduce(l3);
  int lane = threadIdx.x & 63, w = threadIdx.x >> 6;
  if (lane == 0) { sb1[w] = l2; sb2[w] = l3; }
  __syncthreads();
  if (threadIdx.x == 0) {
    l2p[blockIdx.x] = (double)(sb1[0] + sb1[1] + sb1[2] + sb1[3]);
    l3p[blockIdx.x] = (double)(sb2[0] + sb2[1] + sb2[2] + sb2[3]);
  }
}

// ---------------- deterministic final reduce of loss partials --------------
__global__ __launch_bounds__(256) void scalars_k(const double* __restrict__ l1p,
                                                 const double* __restrict__ l2p,
                                                 const double* __restrict__ l3p,
                                                 float* __restrict__ out) {
  __shared__ double sm[256];
  const int t = threadIdx.x;

  double a = 0.0;
  for (int i = t; i < 1024; i += 256) a += l1p[i];
  sm[t] = a;
  __syncthreads();
  for (int s = 128; s; s >>= 1) {
    if (t < s) sm[t] += sm[t + s];
    __syncthreads();
  }
  double L1 = sm[0];
  __syncthreads();

  a = 0.0;
  for (int i = t; i < 768; i += 256) a += l2p[i];
  sm[t] = a;
  __syncthreads();
  for (int s = 128; s; s >>= 1) {
    if (t < s) sm[t] += sm[t + s];
    __syncthreads();
  }
  double L2 = sm[0];
  __syncthreads();

  a = 0.0;
  for (int i = t; i < 768; i += 256) a += l3p[i];
  sm[t] = a;
  __syncthreads();
  for (int s = 128; s; s >>= 1) {
    if (t < s) sm[t] += sm[t + s];
    __syncthreads();
  }
  double L3 = sm[0];

  if (t == 0) {
    out[0] = (float)(0.1 * L1 / 3145728.0);
    out[1] = (float)(0.1 * L2 / 12582912.0);
    out[2] = (float)(-0.1 * L3 / 12582912.0);
  }
}

// ---------------------------------------------------------------------------
extern "C" void kernel_launch(void* const* d_in, const int* in_sizes, int n_in,
                              void* d_out, int out_size, void* d_ws,
                              size_t ws_size, hipStream_t stream) {
  const float* x = (const float*)d_in[0];
  const float* w1 = (const float*)d_in[1];
  const float* w2 = (const float*)d_in[2];
  const float* w3 = (const float*)d_in[3];
  const float* wa = (const float*)d_in[4];
  const float* ws1 = (const float*)d_in[5];
  const float* ws2 = (const float*)d_in[6];
  const float* gb[12];
  for (int i = 0; i < 12; ++i) gb[i] = (const float*)d_in[7 + i];

  float* dout = (float*)d_out;
  float* Aout = dout;                 // [1024,64,16,16]
  float* Sout = dout + 16777216LL;    // [1024,192,8,8]
  float* sc_out = dout + 29360128LL;  // 3 scalars

  // workspace layout (float offsets) — total ~343 MB
  float* wsf = (float*)d_ws;
  unsigned short* y1b = (unsigned short*)(wsf);              // 33.5M ush
  unsigned short* y2b = (unsigned short*)(wsf + 16777216LL); // 67.1M ush
  unsigned short* y3b = (unsigned short*)(wsf + 50331648LL); // 16.8M ush
  unsigned short* y5b = (unsigned short*)(wsf + 58720256LL); // 50.3M ush
  unsigned short* wts = (unsigned short*)(wsf + 83886080LL);
  unsigned short* w2r = wts;                 // 18,432
  unsigned short* w3r = wts + 18432;         // 36,864
  unsigned short* ws1r = wts + 55296;        // 55,296
  unsigned short* ws2r = wts + 110592;       // 331,776
  double* part = (double*)(wsf + 84107264LL);  // 786,432 dbl (max: L5)
  double* l1p = (double*)(wsf + 85680128LL);   // 1024
  double* l2p = l1p + 1024;                    // 768
  double* l3p = l2p + 768;                     // 768
  float* ssL = (float*)(l3p + 768);            // 6 x 384 floats
  float* ss0 = ssL, *ss1 = ssL + 384, *ss2 = ssL + 768;
  float* ss3 = ssL + 1152, *ss4 = ssL + 1536, *ss5 = ssL + 1920;

  // ---- weight reorders (single launch) ----
  wreord_all_k<<<1728, 256, 0, stream>>>(w2, w3, ws1, ws2, w2r, w3r, ws1r, ws2r);

  // ---- L0: conv1 3->32 (fp32) -> y1b bf16 channel-last, fused stats ----
  conv0_k<<<dim3(1024, 4), 256, 0, stream>>>(x, w1, y1b, part);
  finalize_k<<<32, 256, 0, stream>>>(part, 1024, gb[0], gb[1], ss0, 32, 1.0 / 1048576.0);

  // ---- L1: conv2 32->64 (GEMM) -> y2b, fused stats ----
  convgemm_k<32, 0, 32, 36, 64, 64, 32, 32, 1, 8, 2, 4, 2, 4, true>
      <<<dim3(1024, 4, 1), 512, 0, stream>>>(y1b, ss0, w2r, nullptr, y2b, part);
  finalize_k<<<64, 256, 0, stream>>>(part, 4096, gb[2], gb[3], ss1, 64, 1.0 / 1048576.0);

  // ---- L2: conv3 64->64 s2 (GEMM, swizzled+swap LDS) -> y3b, fused stats ----
  convgemm_k<64, 0, 64, 68, 64, 64, 32, 16, 2, 8, 2, 4, 2, 2, true>
      <<<dim3(1024, 2, 1), 512, 0, stream>>>(y2b, ss1, w3r, nullptr, y3b, part);
  finalize_k<<<64, 256, 0, stream>>>(part, 2048, gb[4], gb[5], ss2, 64, 1.0 / 262144.0);

  // ---- L3: convA 1x1 (y3b ch 0..31) -> Aout fp32 raw, fused stats ----
  conv1x1_k<<<dim3(1024, 4), 256, 0, stream>>>(y3b, ss2, wa, Aout, part);
  finalize_k<<<64, 256, 0, stream>>>(part, 1024, gb[6], gb[7], ss3, 64, 1.0 / 262144.0);

  // ---- L4: convS1 32->192 (y3b ch 32..63, GEMM, z-split 2) -> y5b ----
  convgemm_k<64, 32, 32, 36, 192, 96, 16, 16, 1, 16, 2, 4, 3, 4, true>
      <<<dim3(1024, 1, 2), 512, 0, stream>>>(y3b, ss2, ws1r, nullptr, y5b, part);
  finalize_k<<<192, 256, 0, stream>>>(part, 1024, gb[8], gb[9], ss4, 192, 1.0 / 262144.0);

  // ---- L5: convS2 192->192 s2 (GEMM, swizzled+swap LDS) -> Sout raw ----
  convgemm_k<192, 0, 192, 196, 192, 192, 16, 8, 2, 4, 4, 2, 3, 1, false>
      <<<dim3(1024, 2, 1), 512, 0, stream>>>(y5b, ss4, ws2r, Sout, nullptr, part);
  finalize_k<<<192, 256, 0, stream>>>(part, 2048, gb[10], gb[11], ss5, 192, 1.0 / 65536.0);

  // ---- losses (loss23 normalizes S in-place FIRST; convt normalizes A) ----
  loss23_k<<<768, 256, 0, stream>>>(Sout, ss5, l2p, l3p);
  convt_l1_k<<<1024, 256, 0, stream>>>(Aout, Sout, x, ss3, l1p);
  scalars_k<<<1, 256, 0, stream>>>(l1p, l2p, l3p, sc_out);
}

// Round 13
// 659.561 us; speedup vs baseline: 1.0255x; 1.0255x over previous
//
#include <hip/hip_runtime.h>
#include <math.h>

// ---------------------------------------------------------------------------
// Encoder_50414326120900 — round 13:
//  (a) convgemm channel-phased staging (NPH): smaller LDS -> more blocks/CU
//      (L5: 3 phases, 22KB, 4 blk/CU; L2: 2 phases, 41.6KB, 3 blk/CU).
//      r12 lesson: bank conflicts were NOT the critical path; occupancy is.
//  (b) loss23 fused into convt_l1 (S normalized+written-back during staging,
//      l2 fp32 inline, l3 from staged bf16 rows). Kernel deleted.
// ---------------------------------------------------------------------------

typedef __attribute__((ext_vector_type(8))) short short8v;
typedef __attribute__((ext_vector_type(4))) short short4v;
typedef __attribute__((ext_vector_type(4))) float f32x4;

__device__ __forceinline__ unsigned short f2bf(float f) {
  union { float f; unsigned u; } a; a.f = f;
  unsigned r = a.u + 0x7fffu + ((a.u >> 16) & 1u);
  return (unsigned short)(r >> 16);
}
__device__ __forceinline__ float bf2f(unsigned short h) {
  union { unsigned u; float f; } a; a.u = ((unsigned)h) << 16;
  return a.f;
}

__device__ __forceinline__ float wave_reduce(float v) {
#pragma unroll
  for (int off = 32; off; off >>= 1) v += __shfl_down(v, off, 64);
  return v;
}

// ---------------- merged weight reorder -------------------------------------
template <int CI, int CO>
__device__ __forceinline__ void reord1(const float* __restrict__ w,
                                       unsigned short* __restrict__ wr,
                                       int idx) {
  int e = idx & 7;
  int t = idx >> 3;
  int co = t % CO; t /= CO;
  int ci8 = t % (CI / 8);
  int kk = t / (CI / 8);
  int ci = ci8 * 8 + e;
  wr[idx] = f2bf(w[((size_t)co * CI + ci) * 9 + kk]);
}

__global__ __launch_bounds__(256) void wreord_all_k(
    const float* __restrict__ w2, const float* __restrict__ w3,
    const float* __restrict__ ws1, const float* __restrict__ ws2,
    unsigned short* __restrict__ w2r, unsigned short* __restrict__ w3r,
    unsigned short* __restrict__ ws1r, unsigned short* __restrict__ ws2r) {
  int idx = blockIdx.x * 256 + threadIdx.x;
  if (idx < 18432) reord1<32, 64>(w2, w2r, idx);
  else if (idx < 55296) reord1<64, 64>(w3, w3r, idx - 18432);
  else if (idx < 110592) reord1<32, 192>(ws1, ws1r, idx - 55296);
  else if (idx < 442368) reord1<192, 192>(ws2, ws2r, idx - 110592);
}

// ---------------- L0: 3->32 conv 3x3 s1, fp32 math, bf16 out + fused stats --
__global__ __launch_bounds__(256) void conv0_k(const float* __restrict__ in,
                                               const float* __restrict__ w,
                                               unsigned short* __restrict__ outB,
                                               double* __restrict__ part) {
  __shared__ __align__(16) float tile[3][34][36];
  const int b = blockIdx.x;
  const int co0 = blockIdx.y * 8;
  const int tid = threadIdx.x;
  const int row = tid >> 3, x0 = (tid & 7) * 4;
  const int wv = tid >> 6;

  float* tf = &tile[0][0][0];
  for (int i = tid; i < 918; i += 256)
    *(float4*)(tf + i * 4) = make_float4(0.f, 0.f, 0.f, 0.f);
  __syncthreads();
  for (int i = tid; i < 768; i += 256) {
    int x4 = i & 7, yy = (i >> 3) & 31, c = i >> 8;
    float4 v = *(const float4*)&in[(((size_t)b * 3 + c) * 32 + yy) * 32 + x4 * 4];
    float* dst = &tile[c][yy + 1][1 + x4 * 4];
    dst[0] = v.x; dst[1] = v.y; dst[2] = v.z; dst[3] = v.w;
  }
  __syncthreads();

  float acc[4][8];
#pragma unroll
  for (int p = 0; p < 4; ++p)
#pragma unroll
    for (int co = 0; co < 8; ++co) acc[p][co] = 0.f;

#pragma unroll
  for (int c = 0; c < 3; ++c)
#pragma unroll
    for (int ky = 0; ky < 3; ++ky) {
      const float* tr = &tile[c][row + ky][x0];
      float4 vlo = *(const float4*)tr;
      float2 vhi = *(const float2*)(tr + 4);
      float v[6] = {vlo.x, vlo.y, vlo.z, vlo.w, vhi.x, vhi.y};
#pragma unroll
      for (int kx = 0; kx < 3; ++kx)
#pragma unroll
        for (int co = 0; co < 8; ++co) {
          float wvv = w[((size_t)(co0 + co) * 3 + c) * 9 + ky * 3 + kx];
#pragma unroll
          for (int p = 0; p < 4; ++p)
            acc[p][co] = fmaf(v[p + kx], wvv, acc[p][co]);
        }
    }
#pragma unroll
  for (int p = 0; p < 4; ++p) {
    short8v o;
#pragma unroll
    for (int co = 0; co < 8; ++co) o[co] = (short)f2bf(acc[p][co]);
    *(short8v*)&outB[(((size_t)b * 32 + row) * 32 + x0 + p) * 32 + co0] = o;
  }

  float s8[8], q8[8];
#pragma unroll
  for (int co = 0; co < 8; ++co) {
    float s = 0.f, q = 0.f;
#pragma unroll
    for (int p = 0; p < 4; ++p) {
      float v = acc[p][co];
      s += v;
      q = fmaf(v, v, q);
    }
    s8[co] = wave_reduce(s);
    q8[co] = wave_reduce(q);
  }
  __syncthreads();
  float* sb = (float*)tile;
  if ((tid & 63) == 0) {
#pragma unroll
    for (int co = 0; co < 8; ++co) {
      sb[wv * 8 + co] = s8[co];
      sb[32 + wv * 8 + co] = q8[co];
    }
  }
  __syncthreads();
  if (tid < 8) {
    float S = 0.f, Q = 0.f;
#pragma unroll
    for (int k = 0; k < 4; ++k) {
      S += sb[k * 8 + tid];
      Q += sb[32 + k * 8 + tid];
    }
    size_t slot = ((size_t)(co0 + tid) * 1024 + b) * 2;
    part[slot] = (double)S;
    part[slot + 1] = (double)Q;
  }
}

// ---------------- LDS-staged MFMA GEMM-conv 3x3 (pad 1), channel-phased -----
// NPH phases of CIS=CI/NPH channels each; LDS holds one phase -> more blocks
// resident per CU. acc persists across phases. SWZ kept where valid.
template <int CI_T, int CI0, int CI, int NPH, int CIP, int CO, int COB,
          int IHW, int OHW, int STRIDE, int ORPB, int WM, int WN, int CTM,
          int CTN, bool OUT_BF16T>
__global__ __launch_bounds__(512) void convgemm_k(
    const unsigned short* __restrict__ inT, const float* __restrict__ ss,
    const unsigned short* __restrict__ wr_w, float* __restrict__ outF,
    unsigned short* __restrict__ outB, double* __restrict__ part) {
  constexpr int IR = (ORPB - 1) * STRIDE + 3;
  constexpr int IW2 = IHW + 2;
  constexpr int NPX = ORPB * OHW;
  constexpr int NPIX = OHW * OHW;
  constexpr int CIS = CI / NPH;
  constexpr int CPP = CIS / 8;
  constexpr bool SWZ = (STRIDE == 2) && (CPP % 8 == 0);
  static_assert(CI % NPH == 0 && CIS % 32 == 0, "phase split");
  static_assert(WM * WN == 8, "8 waves");
  static_assert(WN * CTN * 16 == NPX, "px tiling");
  static_assert(WM * CTM * 16 == COB, "co tiling");
  static_assert((IR * IW2 * CIP) % 4 == 0, "zero fill");
  static_assert(IR * IW2 * CIP * 2 >= 8 * CTM * 16 * 2 * 4, "stats overlay");
  __shared__ __align__(16) unsigned short st[IR * IW2 * CIP];

  const int b = blockIdx.x;
  const int oy0 = blockIdx.y * ORPB;
  const int co_base = blockIdx.z * COB;
  const int tid = threadIdx.x;
  const int w = tid >> 6, l = tid & 63;
  const int l16 = l & 15, g = l >> 4;
  const int wrow = w / WN, wcol = w % WN;

  {
    uint2 z = make_uint2(0u, 0u);
    uint2* stz = (uint2*)st;
    constexpr int NZ = IR * IW2 * CIP / 4;
    for (int i = tid; i < NZ; i += 512) stz[i] = z;
  }

  int prow[CTN], pxx[CTN];
#pragma unroll
  for (int pn = 0; pn < CTN; ++pn) {
    int pxl = (wcol * CTN + pn) * 16 + l16;
    int ly = pxl / OHW, lx = pxl % OHW;
    prow[pn] = (ly * STRIDE * IW2 + lx * STRIDE) * CIP;
    pxx[pn] = lx * STRIDE;
  }
  const int co_off = co_base + wrow * CTM * 16 + l16;

  f32x4 acc[CTM][CTN];
#pragma unroll
  for (int cm = 0; cm < CTM; ++cm)
#pragma unroll
    for (int pn = 0; pn < CTN; ++pn) {
      f32x4 z = {0.f, 0.f, 0.f, 0.f};
      acc[cm][pn] = z;
    }

  for (int ph = 0; ph < NPH; ++ph) {
    __syncthreads();  // zero-fill done / previous phase's reads done
    {
      const int CH0 = CI0 + ph * CIS;
      constexpr int NCH = IR * IHW * CPP;
      const int r0in = oy0 * STRIDE - 1;
      for (int i = tid; i < NCH; i += 512) {
        int c8 = i % CPP;
        int xx = (i / CPP) % IHW;
        int ir = i / (CPP * IHW);
        int iy = r0in + ir;
        if ((unsigned)iy < (unsigned)IHW) {
          short8v raw = *(const short8v*)&inT[(((size_t)b * IHW + iy) * IHW +
                                              xx) * CI_T + CH0 + c8 * 8];
          f32x4 sc0 = *(const f32x4*)&ss[CH0 + c8 * 8];
          f32x4 sc1 = *(const f32x4*)&ss[CH0 + c8 * 8 + 4];
          f32x4 sh0 = *(const f32x4*)&ss[CI_T + CH0 + c8 * 8];
          f32x4 sh1 = *(const f32x4*)&ss[CI_T + CH0 + c8 * 8 + 4];
          short4v lo, hi;
#pragma unroll
          for (int e = 0; e < 4; ++e) {
            float f = bf2f((unsigned short)raw[e]);
            f = fmaxf(fmaf(f, sc0[e], sh0[e]), 0.f);
            lo[e] = (short)f2bf(f);
          }
#pragma unroll
          for (int e = 0; e < 4; ++e) {
            float f = bf2f((unsigned short)raw[e + 4]);
            f = fmaxf(fmaf(f, sc1[e], sh1[e]), 0.f);
            hi[e] = (short)f2bf(f);
          }
          int xcol = xx + 1;
          int gran = SWZ ? (c8 ^ (xcol & 7)) : c8;
          int pp = SWZ ? ((xcol >> 1) & 1) : 0;
          unsigned short* dst = &st[(ir * IW2 + xcol) * CIP + gran * 8];
          *(short4v*)(dst + 4 * pp) = lo;
          *(short4v*)(dst + 4 * (1 - pp)) = hi;
        }
      }
    }
    __syncthreads();

#pragma unroll 3
    for (int kk = 0; kk < 9; ++kk) {
      const int ky = kk / 3, kx = kk % 3;
      const int rowadd = (ky * IW2 + kx) * CIP;
#pragma unroll
      for (int cs = 0; cs < CIS / 32; ++cs) {
        short8v bfr[CTN];
#pragma unroll
        for (int pn = 0; pn < CTN; ++pn) {
          int col = pxx[pn] + kx;
          int gran = cs * 4 + g;
          int pp = 0;
          if (SWZ) {
            gran ^= (col & 7);
            pp = (col >> 1) & 1;
          }
          const unsigned short* bp = &st[prow[pn] + rowadd + gran * 8];
          short4v lo = *(const short4v*)(bp + 4 * pp);
          short4v hi = *(const short4v*)(bp + 4 * (1 - pp));
          short8v v = {lo[0], lo[1], lo[2], lo[3], hi[0], hi[1], hi[2], hi[3]};
          bfr[pn] = v;
        }
        const unsigned short* wb =
            wr_w + ((size_t)(kk * (CI / 8) + ph * CPP + cs * 4 + g) * CO +
                    co_off) * 8;
        short8v afr[CTM];
#pragma unroll
        for (int cm = 0; cm < CTM; ++cm)
          afr[cm] = *(const short8v*)(wb + cm * 128);
#pragma unroll
        for (int cm = 0; cm < CTM; ++cm)
#pragma unroll
          for (int pn = 0; pn < CTN; ++pn)
            acc[cm][pn] = __builtin_amdgcn_mfma_f32_16x16x32_bf16(
                afr[cm], bfr[pn], acc[cm][pn], 0, 0, 0);
      }
    }
  }

#pragma unroll
  for (int cm = 0; cm < CTM; ++cm)
#pragma unroll
    for (int pn = 0; pn < CTN; ++pn) {
      int pxl = (wcol * CTN + pn) * 16 + l16;
      size_t pxg = (size_t)oy0 * OHW + pxl;
      int co = co_base + (wrow * CTM + cm) * 16 + g * 4;
      if (OUT_BF16T) {
        unsigned d0 = (unsigned)f2bf(acc[cm][pn][0]) |
                      ((unsigned)f2bf(acc[cm][pn][1]) << 16);
        unsigned d1 = (unsigned)f2bf(acc[cm][pn][2]) |
                      ((unsigned)f2bf(acc[cm][pn][3]) << 16);
        unsigned* dst = (unsigned*)&outB[((size_t)b * NPIX + pxg) * CO + co];
        dst[0] = d0;
        dst[1] = d1;
      } else {
#pragma unroll
        for (int r = 0; r < 4; ++r)
          outF[((size_t)b * CO + co + r) * NPIX + pxg] = acc[cm][pn][r];
      }
    }

  float sst[CTM][4], qst[CTM][4];
#pragma unroll
  for (int cm = 0; cm < CTM; ++cm)
#pragma unroll
    for (int r = 0; r < 4; ++r) {
      float s = 0.f, q = 0.f;
#pragma unroll
      for (int pn = 0; pn < CTN; ++pn) {
        float v = acc[cm][pn][r];
        s += v;
        q = fmaf(v, v, q);
      }
#pragma unroll
      for (int mask = 1; mask < 16; mask <<= 1) {
        s += __shfl_xor(s, mask, 64);
        q += __shfl_xor(q, mask, 64);
      }
      sst[cm][r] = s;
      qst[cm][r] = q;
    }
  __syncthreads();
  float* sbuf = (float*)st;
  float* qbuf = sbuf + 8 * CTM * 16;
  if (l16 == 0) {
#pragma unroll
    for (int cm = 0; cm < CTM; ++cm)
#pragma unroll
      for (int r = 0; r < 4; ++r) {
        sbuf[((w * CTM + cm) * 4 + g) * 4 + r] = sst[cm][r];
        qbuf[((w * CTM + cm) * 4 + g) * 4 + r] = qst[cm][r];
      }
  }
  __syncthreads();
  if (tid < COB) {
    int wrow_t = tid / (CTM * 16);
    int rem = tid % (CTM * 16);
    float S = 0.f, Q = 0.f;
#pragma unroll
    for (int j = 0; j < WN; ++j) {
      int wvx = wrow_t * WN + j;
      S += sbuf[(wvx * CTM) * 16 + rem];
      Q += qbuf[(wvx * CTM) * 16 + rem];
    }
    const int blk = blockIdx.x * gridDim.y + blockIdx.y;
    const int nblk = 1024 * gridDim.y;
    size_t slot = ((size_t)(co_base + tid) * nblk + blk) * 2;
    part[slot] = (double)S;
    part[slot + 1] = (double)Q;
  }
}

// ---------------- BN scale/shift — parallel deterministic tree reduce -------
__global__ __launch_bounds__(256) void finalize_k(
    const double* __restrict__ part, int NB, const float* __restrict__ g,
    const float* __restrict__ bb, float* __restrict__ ss, int C, double invN) {
  __shared__ double sms[256], smq[256];
  const int c = blockIdx.x;
  const int t = threadIdx.x;
  double s = 0.0, q = 0.0;
  const double* base = part + (size_t)c * NB * 2;
  for (int i = t; i < NB; i += 256) {
    s += base[i * 2];
    q += base[i * 2 + 1];
  }
  sms[t] = s;
  smq[t] = q;
  __syncthreads();
  for (int st = 128; st; st >>= 1) {
    if (t < st) {
      sms[t] += sms[t + st];
      smq[t] += smq[t + st];
    }
    __syncthreads();
  }
  if (t == 0) {
    double mean = sms[0] * invN;
    double var = smq[0] * invN - mean * mean;
    float scale = g[c] * rsqrtf((float)var + 1e-5f);
    float shift = bb[c] - (float)mean * scale;
    ss[c] = scale;
    ss[C + c] = shift;
  }
}

// ---------------- L3: 1x1 conv from channel-last bf16 y3b + fused stats -----
__global__ __launch_bounds__(256) void conv1x1_k(
    const unsigned short* __restrict__ inT, const float* __restrict__ ss,
    const float* __restrict__ w, float* __restrict__ out,
    double* __restrict__ part) {
  __shared__ float sb1x[4][16], qb1x[4][16];
  const int b = blockIdx.x;
  const int co0 = blockIdx.y * 16;
  const int px = threadIdx.x;
  const int wv = threadIdx.x >> 6;
  float acc[16];
#pragma unroll
  for (int co = 0; co < 16; ++co) acc[co] = 0.f;
  const unsigned short* rowp = inT + ((size_t)b * 256 + px) * 64;
#pragma unroll
  for (int c8 = 0; c8 < 4; ++c8) {
    short8v raw = *(const short8v*)(rowp + c8 * 8);
#pragma unroll
    for (int e = 0; e < 8; ++e) {
      int c = c8 * 8 + e;
      float f = bf2f((unsigned short)raw[e]);
      f = fmaxf(fmaf(f, ss[c], ss[64 + c]), 0.f);
#pragma unroll
      for (int co = 0; co < 16; ++co)
        acc[co] = fmaf(f, w[(co0 + co) * 32 + c], acc[co]);
    }
  }
#pragma unroll
  for (int co = 0; co < 16; ++co)
    out[((size_t)b * 64 + co0 + co) * 256 + px] = acc[co];

#pragma unroll
  for (int co = 0; co < 16; ++co) {
    float s = wave_reduce(acc[co]);
    float q = wave_reduce(acc[co] * acc[co]);
    if ((threadIdx.x & 63) == 0) {
      sb1x[wv][co] = s;
      qb1x[wv][co] = q;
    }
  }
  __syncthreads();
  if (px < 16) {
    float S = 0.f, Q = 0.f;
#pragma unroll
    for (int k = 0; k < 4; ++k) {
      S += sb1x[k][px];
      Q += qb1x[k][px];
    }
    size_t slot = ((size_t)(co0 + px) * 1024 + b) * 2;
    part[slot] = (double)S;
    part[slot + 1] = (double)Q;
  }
}

// ---------------- convT + ALL losses (l1,l2,l3) ------------------------------
// A raw -> normalize (write back) ; S raw -> normalize (write back) + l2 fp32
// inline + Sb bf16 ; l3 from Sb rows ; convT via MFMA -> l1.
__global__ __launch_bounds__(256) void convt_l1_k(
    float* __restrict__ A, float* __restrict__ S, const float* __restrict__ x,
    const float* __restrict__ ssA, const float* __restrict__ ssS,
    double* __restrict__ l1p, double* __restrict__ l2p,
    double* __restrict__ l3p) {
  __shared__ unsigned short Ab[8][256][8];
  __shared__ unsigned short Sb[4][16][3][72];
  __shared__ float sbred[4], sbl2[4], sbl3[4];
  const int b = blockIdx.x, tid = threadIdx.x;
  const int w = tid >> 6, l = tid & 63;
  const int g = l >> 4, c = l & 15;
  const int pa = w >> 1, pb = w & 1;

  float* Ag = A + (size_t)b * 16384;
  for (int dp = 0; dp < 32; ++dp) {
    int d = dp * 2;
    float f0 = Ag[(size_t)d * 256 + tid];
    float f1 = Ag[(size_t)(d + 1) * 256 + tid];
    f0 = fmaxf(fmaf(f0, ssA[d], ssA[64 + d]), 0.f);
    f1 = fmaxf(fmaf(f1, ssA[d + 1], ssA[64 + d + 1]), 0.f);
    Ag[(size_t)d * 256 + tid] = f0;
    Ag[(size_t)(d + 1) * 256 + tid] = f1;
    unsigned lo = f2bf(f0);
    unsigned hi = f2bf(f1);
    *(unsigned*)&Ab[d >> 3][tid][d & 7] = lo | (hi << 16);
  }

  float* Sg = S + (size_t)b * 12288;
  float l2loc = 0.f;
  for (int i = tid; i < 12288; i += 256) {
    float raw = Sg[i];
    int cch = i >> 6;
    float f = fmaxf(fmaf(raw, ssS[cch], ssS[192 + cch]), 0.f);
    Sg[i] = f;      // normalized S to d_out
    l2loc += f;     // relu(f) == f
    int tap = i & 63;
    int d = cch / 3, t = cch - 3 * d;
    int ky = tap >> 3, kx = tap & 7;
    int par = (((ky & 1) ^ 1) << 1) | ((kx & 1) ^ 1);
    Sb[par][(ky >> 1) * 4 + (kx >> 1)][t][d] = f2bf(f);
  }
  __syncthreads();

  // l3 entropy: one (par,tap,t) row of 64 contiguous bf16 per thread (tid<192)
  float l3loc = 0.f;
  if (tid < 192) {
    int par = tid / 48, rr = tid - par * 48;
    int tap = rr / 3, t = rr - tap * 3;
    const unsigned short* rowp = &Sb[par][tap][t][0];
    short8v rv[8];
#pragma unroll
    for (int k = 0; k < 8; ++k) rv[k] = *(const short8v*)(rowp + k * 8);
    float m = -1e30f;
#pragma unroll
    for (int k = 0; k < 8; ++k)
#pragma unroll
      for (int e = 0; e < 8; ++e)
        m = fmaxf(m, bf2f((unsigned short)rv[k][e]));
    float Z = 0.f;
#pragma unroll
    for (int k = 0; k < 8; ++k)
#pragma unroll
      for (int e = 0; e < 8; ++e)
        Z += expf(bf2f((unsigned short)rv[k][e]) - m);
    float lZ = logf(Z);
#pragma unroll
    for (int k = 0; k < 8; ++k)
#pragma unroll
      for (int e = 0; e < 8; ++e) {
        float lp = bf2f((unsigned short)rv[k][e]) - m - lZ;
        l3loc = fmaf(expf(lp), lp, l3loc);
      }
  }

  f32x4 acc[16];
#pragma unroll
  for (int nt = 0; nt < 16; ++nt) {
    f32x4 z = {0.f, 0.f, 0.f, 0.f};
    acc[nt] = z;
  }

  const int shy = 1 + pa, shx = 1 + pb;
  for (int s = 0; s < 32; ++s) {
    const int tap = s >> 1;
    const int m = tap >> 2, n = tap & 3;
    const int dh = s & 1;
    short8v afr = {0, 0, 0, 0, 0, 0, 0, 0};
    if (c < 3) afr = *(const short8v*)&Sb[w][tap][c][dh * 32 + g * 8];
    const int ix = c + shx - n;
    const bool xok = (unsigned)ix < 16u;
    const int dblk = dh * 4 + g;
#pragma unroll
    for (int nt = 0; nt < 16; ++nt) {
      int iy = nt + shy - m;
      if ((unsigned)iy >= 16u) continue;
      short8v bfr = {0, 0, 0, 0, 0, 0, 0, 0};
      if (xok) bfr = *(const short8v*)&Ab[dblk][iy * 16 + ix][0];
      acc[nt] = __builtin_amdgcn_mfma_f32_16x16x32_bf16(afr, bfr, acc[nt],
                                                        0, 0, 0);
    }
  }

  float loc = 0.f;
  if (g == 0) {
    const float* xg = x + (size_t)b * 3072;
#pragma unroll
    for (int nt = 0; nt < 16; ++nt) {
      int oy = 2 * nt + pa, ox = 2 * c + pb;
#pragma unroll
      for (int r = 0; r < 3; ++r) {
        float recon = 1.f / (1.f + expf(-acc[nt][r]));
        float img = 1.f / (1.f + expf(-xg[r * 1024 + oy * 32 + ox]));
        float dd = img - recon;
        loc = fmaf(dd, dd, loc);
      }
    }
  }
  loc = wave_reduce(loc);
  l2loc = wave_reduce(l2loc);
  l3loc = wave_reduce(l3loc);
  if (l == 0) { sbred[w] = loc; sbl2[w] = l2loc; sbl3[w] = l3loc; }
  __syncthreads();
  if (tid == 0) {
    l1p[b] = (double)(sbred[0] + sbred[1] + sbred[2] + sbred[3]);
    l2p[b] = (double)(sbl2[0] + sbl2[1] + sbl2[2] + sbl2[3]);
    l3p[b] = (double)(sbl3[0] + sbl3[1] + sbl3[2] + sbl3[3]);
  }
}

// ---------------- deterministic final reduce of loss partials --------------
__global__ __launch_bounds__(256) void scalars_k(const double* __restrict__ l1p,
                                                 const double* __restrict__ l2p,
                                                 const double* __restrict__ l3p,
                                                 float* __restrict__ out) {
  __shared__ double sm[256];
  const int t = threadIdx.x;

  double a = 0.0;
  for (int i = t; i < 1024; i += 256) a += l1p[i];
  sm[t] = a;
  __syncthreads();
  for (int s = 128; s; s >>= 1) {
    if (t < s) sm[t] += sm[t + s];
    __syncthreads();
  }
  double L1 = sm[0];
  __syncthreads();

  a = 0.0;
  for (int i = t; i < 1024; i += 256) a += l2p[i];
  sm[t] = a;
  __syncthreads();
  for (int s = 128; s; s >>= 1) {
    if (t < s) sm[t] += sm[t + s];
    __syncthreads();
  }
  double L2 = sm[0];
  __syncthreads();

  a = 0.0;
  for (int i = t; i < 1024; i += 256) a += l3p[i];
  sm[t] = a;
  __syncthreads();
  for (int s = 128; s; s >>= 1) {
    if (t < s) sm[t] += sm[t + s];
    __syncthreads();
  }
  double L3 = sm[0];

  if (t == 0) {
    out[0] = (float)(0.1 * L1 / 3145728.0);
    out[1] = (float)(0.1 * L2 / 12582912.0);
    out[2] = (float)(-0.1 * L3 / 12582912.0);
  }
}

// ---------------------------------------------------------------------------
extern "C" void kernel_launch(void* const* d_in, const int* in_sizes, int n_in,
                              void* d_out, int out_size, void* d_ws,
                              size_t ws_size, hipStream_t stream) {
  const float* x = (const float*)d_in[0];
  const float* w1 = (const float*)d_in[1];
  const float* w2 = (const float*)d_in[2];
  const float* w3 = (const float*)d_in[3];
  const float* wa = (const float*)d_in[4];
  const float* ws1 = (const float*)d_in[5];
  const float* ws2 = (const float*)d_in[6];
  const float* gb[12];
  for (int i = 0; i < 12; ++i) gb[i] = (const float*)d_in[7 + i];

  float* dout = (float*)d_out;
  float* Aout = dout;                 // [1024,64,16,16]
  float* Sout = dout + 16777216LL;    // [1024,192,8,8]
  float* sc_out = dout + 29360128LL;  // 3 scalars

  // workspace layout (float offsets) — total ~343 MB
  float* wsf = (float*)d_ws;
  unsigned short* y1b = (unsigned short*)(wsf);              // 33.5M ush
  unsigned short* y2b = (unsigned short*)(wsf + 16777216LL); // 67.1M ush
  unsigned short* y3b = (unsigned short*)(wsf + 50331648LL); // 16.8M ush
  unsigned short* y5b = (unsigned short*)(wsf + 58720256LL); // 50.3M ush
  unsigned short* wts = (unsigned short*)(wsf + 83886080LL);
  unsigned short* w2r = wts;                 // 18,432
  unsigned short* w3r = wts + 18432;         // 36,864
  unsigned short* ws1r = wts + 55296;        // 55,296
  unsigned short* ws2r = wts + 110592;       // 331,776
  double* part = (double*)(wsf + 84107264LL);  // 786,432 dbl (max: L5)
  double* l1p = (double*)(wsf + 85680128LL);   // 1024
  double* l2p = l1p + 1024;                    // 1024
  double* l3p = l2p + 1024;                    // 1024
  float* ssL = (float*)(l3p + 1024);           // 6 x 384 floats
  float* ss0 = ssL, *ss1 = ssL + 384, *ss2 = ssL + 768;
  float* ss3 = ssL + 1152, *ss4 = ssL + 1536, *ss5 = ssL + 1920;

  // ---- weight reorders (single launch) ----
  wreord_all_k<<<1728, 256, 0, stream>>>(w2, w3, ws1, ws2, w2r, w3r, ws1r, ws2r);

  // ---- L0: conv1 3->32 (fp32) -> y1b bf16 channel-last, fused stats ----
  conv0_k<<<dim3(1024, 4), 256, 0, stream>>>(x, w1, y1b, part);
  finalize_k<<<32, 256, 0, stream>>>(part, 1024, gb[0], gb[1], ss0, 32, 1.0 / 1048576.0);

  // ---- L1: conv2 32->64 (GEMM, 1 phase) -> y2b ----
  convgemm_k<32, 0, 32, 1, 36, 64, 64, 32, 32, 1, 8, 2, 4, 2, 4, true>
      <<<dim3(1024, 4, 1), 512, 0, stream>>>(y1b, ss0, w2r, nullptr, y2b, part);
  finalize_k<<<64, 256, 0, stream>>>(part, 4096, gb[2], gb[3], ss1, 64, 1.0 / 1048576.0);

  // ---- L2: conv3 64->64 s2 (GEMM, 2 phases, 41.6KB LDS) -> y3b ----
  convgemm_k<64, 0, 64, 2, 36, 64, 64, 32, 16, 2, 8, 2, 4, 2, 2, true>
      <<<dim3(1024, 2, 1), 512, 0, stream>>>(y2b, ss1, w3r, nullptr, y3b, part);
  finalize_k<<<64, 256, 0, stream>>>(part, 2048, gb[4], gb[5], ss2, 64, 1.0 / 262144.0);

  // ---- L3: convA 1x1 (y3b ch 0..31) -> Aout fp32 raw, fused stats ----
  conv1x1_k<<<dim3(1024, 4), 256, 0, stream>>>(y3b, ss2, wa, Aout, part);
  finalize_k<<<64, 256, 0, stream>>>(part, 1024, gb[6], gb[7], ss3, 64, 1.0 / 262144.0);

  // ---- L4: convS1 32->192 (y3b ch 32..63, GEMM, z-split 2) -> y5b ----
  convgemm_k<64, 32, 32, 1, 36, 192, 96, 16, 16, 1, 16, 2, 4, 3, 4, true>
      <<<dim3(1024, 1, 2), 512, 0, stream>>>(y3b, ss2, ws1r, nullptr, y5b, part);
  finalize_k<<<192, 256, 0, stream>>>(part, 1024, gb[8], gb[9], ss4, 192, 1.0 / 262144.0);

  // ---- L5: convS2 192->192 s2 (GEMM, 3 phases, 22KB LDS) -> Sout raw ----
  convgemm_k<192, 0, 192, 3, 68, 192, 192, 16, 8, 2, 4, 4, 2, 3, 1, false>
      <<<dim3(1024, 2, 1), 512, 0, stream>>>(y5b, ss4, ws2r, Sout, nullptr, part);
  finalize_k<<<192, 256, 0, stream>>>(part, 2048, gb[10], gb[11], ss5, 192, 1.0 / 65536.0);

  // ---- convT + all losses (normalizes A and S in place) ----
  convt_l1_k<<<1024, 256, 0, stream>>>(Aout, Sout, x, ss3, ss5, l1p, l2p, l3p);
  scalars_k<<<1, 256, 0, stream>>>(l1p, l2p, l3p, sc_out);
}

// Round 14
// 655.207 us; speedup vs baseline: 1.0323x; 1.0066x over previous
//
#include <hip/hip_runtime.h>
#include <math.h>

// ---------------------------------------------------------------------------
// Encoder_50414326120900 — round 13:
//  (a) convgemm channel-phased staging (NPH): smaller LDS -> more blocks/CU
//      (L5: 3 phases, 22KB, 4 blk/CU; L2: 2 phases, 41.6KB, 3 blk/CU).
//      r12 lesson: bank conflicts were NOT the critical path; occupancy is.
//  (b) loss23 fused into convt_l1 (S normalized+written-back during staging,
//      l2 fp32 inline, l3 from staged bf16 rows). Kernel deleted.
// ---------------------------------------------------------------------------

typedef __attribute__((ext_vector_type(8))) short short8v;
typedef __attribute__((ext_vector_type(4))) short short4v;
typedef __attribute__((ext_vector_type(4))) float f32x4;

__device__ __forceinline__ unsigned short f2bf(float f) {
  union { float f; unsigned u; } a; a.f = f;
  unsigned r = a.u + 0x7fffu + ((a.u >> 16) & 1u);
  return (unsigned short)(r >> 16);
}
__device__ __forceinline__ float bf2f(unsigned short h) {
  union { unsigned u; float f; } a; a.u = ((unsigned)h) << 16;
  return a.f;
}

__device__ __forceinline__ float wave_reduce(float v) {
#pragma unroll
  for (int off = 32; off; off >>= 1) v += __shfl_down(v, off, 64);
  return v;
}

// ---------------- merged weight reorder -------------------------------------
template <int CI, int CO>
__device__ __forceinline__ void reord1(const float* __restrict__ w,
                                       unsigned short* __restrict__ wr,
                                       int idx) {
  int e = idx & 7;
  int t = idx >> 3;
  int co = t % CO; t /= CO;
  int ci8 = t % (CI / 8);
  int kk = t / (CI / 8);
  int ci = ci8 * 8 + e;
  wr[idx] = f2bf(w[((size_t)co * CI + ci) * 9 + kk]);
}

__global__ __launch_bounds__(256) void wreord_all_k(
    const float* __restrict__ w2, const float* __restrict__ w3,
    const float* __restrict__ ws1, const float* __restrict__ ws2,
    unsigned short* __restrict__ w2r, unsigned short* __restrict__ w3r,
    unsigned short* __restrict__ ws1r, unsigned short* __restrict__ ws2r) {
  int idx = blockIdx.x * 256 + threadIdx.x;
  if (idx < 18432) reord1<32, 64>(w2, w2r, idx);
  else if (idx < 55296) reord1<64, 64>(w3, w3r, idx - 18432);
  else if (idx < 110592) reord1<32, 192>(ws1, ws1r, idx - 55296);
  else if (idx < 442368) reord1<192, 192>(ws2, ws2r, idx - 110592);
}

// ---------------- L0: 3->32 conv 3x3 s1, fp32 math, bf16 out + fused stats --
__global__ __launch_bounds__(256) void conv0_k(const float* __restrict__ in,
                                               const float* __restrict__ w,
                                               unsigned short* __restrict__ outB,
                                               double* __restrict__ part) {
  __shared__ __align__(16) float tile[3][34][36];
  const int b = blockIdx.x;
  const int co0 = blockIdx.y * 8;
  const int tid = threadIdx.x;
  const int row = tid >> 3, x0 = (tid & 7) * 4;
  const int wv = tid >> 6;

  float* tf = &tile[0][0][0];
  for (int i = tid; i < 918; i += 256)
    *(float4*)(tf + i * 4) = make_float4(0.f, 0.f, 0.f, 0.f);
  __syncthreads();
  for (int i = tid; i < 768; i += 256) {
    int x4 = i & 7, yy = (i >> 3) & 31, c = i >> 8;
    float4 v = *(const float4*)&in[(((size_t)b * 3 + c) * 32 + yy) * 32 + x4 * 4];
    float* dst = &tile[c][yy + 1][1 + x4 * 4];
    dst[0] = v.x; dst[1] = v.y; dst[2] = v.z; dst[3] = v.w;
  }
  __syncthreads();

  float acc[4][8];
#pragma unroll
  for (int p = 0; p < 4; ++p)
#pragma unroll
    for (int co = 0; co < 8; ++co) acc[p][co] = 0.f;

#pragma unroll
  for (int c = 0; c < 3; ++c)
#pragma unroll
    for (int ky = 0; ky < 3; ++ky) {
      const float* tr = &tile[c][row + ky][x0];
      float4 vlo = *(const float4*)tr;
      float2 vhi = *(const float2*)(tr + 4);
      float v[6] = {vlo.x, vlo.y, vlo.z, vlo.w, vhi.x, vhi.y};
#pragma unroll
      for (int kx = 0; kx < 3; ++kx)
#pragma unroll
        for (int co = 0; co < 8; ++co) {
          float wvv = w[((size_t)(co0 + co) * 3 + c) * 9 + ky * 3 + kx];
#pragma unroll
          for (int p = 0; p < 4; ++p)
            acc[p][co] = fmaf(v[p + kx], wvv, acc[p][co]);
        }
    }
#pragma unroll
  for (int p = 0; p < 4; ++p) {
    short8v o;
#pragma unroll
    for (int co = 0; co < 8; ++co) o[co] = (short)f2bf(acc[p][co]);
    *(short8v*)&outB[(((size_t)b * 32 + row) * 32 + x0 + p) * 32 + co0] = o;
  }

  float s8[8], q8[8];
#pragma unroll
  for (int co = 0; co < 8; ++co) {
    float s = 0.f, q = 0.f;
#pragma unroll
    for (int p = 0; p < 4; ++p) {
      float v = acc[p][co];
      s += v;
      q = fmaf(v, v, q);
    }
    s8[co] = wave_reduce(s);
    q8[co] = wave_reduce(q);
  }
  __syncthreads();
  float* sb = (float*)tile;
  if ((tid & 63) == 0) {
#pragma unroll
    for (int co = 0; co < 8; ++co) {
      sb[wv * 8 + co] = s8[co];
      sb[32 + wv * 8 + co] = q8[co];
    }
  }
  __syncthreads();
  if (tid < 8) {
    float S = 0.f, Q = 0.f;
#pragma unroll
    for (int k = 0; k < 4; ++k) {
      S += sb[k * 8 + tid];
      Q += sb[32 + k * 8 + tid];
    }
    size_t slot = ((size_t)(co0 + tid) * 1024 + b) * 2;
    part[slot] = (double)S;
    part[slot + 1] = (double)Q;
  }
}

// ---------------- LDS-staged MFMA GEMM-conv 3x3 (pad 1), channel-phased -----
// NPH phases of CIS=CI/NPH channels each; LDS holds one phase -> more blocks
// resident per CU. acc persists across phases. SWZ kept where valid.
template <int CI_T, int CI0, int CI, int NPH, int CIP, int CO, int COB,
          int IHW, int OHW, int STRIDE, int ORPB, int WM, int WN, int CTM,
          int CTN, bool OUT_BF16T>
__global__ __launch_bounds__(512) void convgemm_k(
    const unsigned short* __restrict__ inT, const float* __restrict__ ss,
    const unsigned short* __restrict__ wr_w, float* __restrict__ outF,
    unsigned short* __restrict__ outB, double* __restrict__ part) {
  constexpr int IR = (ORPB - 1) * STRIDE + 3;
  constexpr int IW2 = IHW + 2;
  constexpr int NPX = ORPB * OHW;
  constexpr int NPIX = OHW * OHW;
  constexpr int CIS = CI / NPH;
  constexpr int CPP = CIS / 8;
  constexpr bool SWZ = (STRIDE == 2) && (CPP % 8 == 0);
  static_assert(CI % NPH == 0 && CIS % 32 == 0, "phase split");
  static_assert(WM * WN == 8, "8 waves");
  static_assert(WN * CTN * 16 == NPX, "px tiling");
  static_assert(WM * CTM * 16 == COB, "co tiling");
  static_assert((IR * IW2 * CIP) % 4 == 0, "zero fill");
  static_assert(IR * IW2 * CIP * 2 >= 8 * CTM * 16 * 2 * 4, "stats overlay");
  __shared__ __align__(16) unsigned short st[IR * IW2 * CIP];

  const int b = blockIdx.x;
  const int oy0 = blockIdx.y * ORPB;
  const int co_base = blockIdx.z * COB;
  const int tid = threadIdx.x;
  const int w = tid >> 6, l = tid & 63;
  const int l16 = l & 15, g = l >> 4;
  const int wrow = w / WN, wcol = w % WN;

  {
    uint2 z = make_uint2(0u, 0u);
    uint2* stz = (uint2*)st;
    constexpr int NZ = IR * IW2 * CIP / 4;
    for (int i = tid; i < NZ; i += 512) stz[i] = z;
  }

  int prow[CTN], pxx[CTN];
#pragma unroll
  for (int pn = 0; pn < CTN; ++pn) {
    int pxl = (wcol * CTN + pn) * 16 + l16;
    int ly = pxl / OHW, lx = pxl % OHW;
    prow[pn] = (ly * STRIDE * IW2 + lx * STRIDE) * CIP;
    pxx[pn] = lx * STRIDE;
  }
  const int co_off = co_base + wrow * CTM * 16 + l16;

  f32x4 acc[CTM][CTN];
#pragma unroll
  for (int cm = 0; cm < CTM; ++cm)
#pragma unroll
    for (int pn = 0; pn < CTN; ++pn) {
      f32x4 z = {0.f, 0.f, 0.f, 0.f};
      acc[cm][pn] = z;
    }

  for (int ph = 0; ph < NPH; ++ph) {
    __syncthreads();  // zero-fill done / previous phase's reads done
    {
      const int CH0 = CI0 + ph * CIS;
      constexpr int NCH = IR * IHW * CPP;
      const int r0in = oy0 * STRIDE - 1;
      for (int i = tid; i < NCH; i += 512) {
        int c8 = i % CPP;
        int xx = (i / CPP) % IHW;
        int ir = i / (CPP * IHW);
        int iy = r0in + ir;
        if ((unsigned)iy < (unsigned)IHW) {
          short8v raw = *(const short8v*)&inT[(((size_t)b * IHW + iy) * IHW +
                                              xx) * CI_T + CH0 + c8 * 8];
          f32x4 sc0 = *(const f32x4*)&ss[CH0 + c8 * 8];
          f32x4 sc1 = *(const f32x4*)&ss[CH0 + c8 * 8 + 4];
          f32x4 sh0 = *(const f32x4*)&ss[CI_T + CH0 + c8 * 8];
          f32x4 sh1 = *(const f32x4*)&ss[CI_T + CH0 + c8 * 8 + 4];
          short4v lo, hi;
#pragma unroll
          for (int e = 0; e < 4; ++e) {
            float f = bf2f((unsigned short)raw[e]);
            f = fmaxf(fmaf(f, sc0[e], sh0[e]), 0.f);
            lo[e] = (short)f2bf(f);
          }
#pragma unroll
          for (int e = 0; e < 4; ++e) {
            float f = bf2f((unsigned short)raw[e + 4]);
            f = fmaxf(fmaf(f, sc1[e], sh1[e]), 0.f);
            hi[e] = (short)f2bf(f);
          }
          int xcol = xx + 1;
          int gran = SWZ ? (c8 ^ (xcol & 7)) : c8;
          int pp = SWZ ? ((xcol >> 1) & 1) : 0;
          unsigned short* dst = &st[(ir * IW2 + xcol) * CIP + gran * 8];
          *(short4v*)(dst + 4 * pp) = lo;
          *(short4v*)(dst + 4 * (1 - pp)) = hi;
        }
      }
    }
    __syncthreads();

#pragma unroll 3
    for (int kk = 0; kk < 9; ++kk) {
      const int ky = kk / 3, kx = kk % 3;
      const int rowadd = (ky * IW2 + kx) * CIP;
#pragma unroll
      for (int cs = 0; cs < CIS / 32; ++cs) {
        short8v bfr[CTN];
#pragma unroll
        for (int pn = 0; pn < CTN; ++pn) {
          int col = pxx[pn] + kx;
          int gran = cs * 4 + g;
          int pp = 0;
          if (SWZ) {
            gran ^= (col & 7);
            pp = (col >> 1) & 1;
          }
          const unsigned short* bp = &st[prow[pn] + rowadd + gran * 8];
          short4v lo = *(const short4v*)(bp + 4 * pp);
          short4v hi = *(const short4v*)(bp + 4 * (1 - pp));
          short8v v = {lo[0], lo[1], lo[2], lo[3], hi[0], hi[1], hi[2], hi[3]};
          bfr[pn] = v;
        }
        const unsigned short* wb =
            wr_w + ((size_t)(kk * (CI / 8) + ph * CPP + cs * 4 + g) * CO +
                    co_off) * 8;
        short8v afr[CTM];
#pragma unroll
        for (int cm = 0; cm < CTM; ++cm)
          afr[cm] = *(const short8v*)(wb + cm * 128);
#pragma unroll
        for (int cm = 0; cm < CTM; ++cm)
#pragma unroll
          for (int pn = 0; pn < CTN; ++pn)
            acc[cm][pn] = __builtin_amdgcn_mfma_f32_16x16x32_bf16(
                afr[cm], bfr[pn], acc[cm][pn], 0, 0, 0);
      }
    }
  }

#pragma unroll
  for (int cm = 0; cm < CTM; ++cm)
#pragma unroll
    for (int pn = 0; pn < CTN; ++pn) {
      int pxl = (wcol * CTN + pn) * 16 + l16;
      size_t pxg = (size_t)oy0 * OHW + pxl;
      int co = co_base + (wrow * CTM + cm) * 16 + g * 4;
      if (OUT_BF16T) {
        unsigned d0 = (unsigned)f2bf(acc[cm][pn][0]) |
                      ((unsigned)f2bf(acc[cm][pn][1]) << 16);
        unsigned d1 = (unsigned)f2bf(acc[cm][pn][2]) |
                      ((unsigned)f2bf(acc[cm][pn][3]) << 16);
        unsigned* dst = (unsigned*)&outB[((size_t)b * NPIX + pxg) * CO + co];
        dst[0] = d0;
        dst[1] = d1;
      } else {
#pragma unroll
        for (int r = 0; r < 4; ++r)
          outF[((size_t)b * CO + co + r) * NPIX + pxg] = acc[cm][pn][r];
      }
    }

  float sst[CTM][4], qst[CTM][4];
#pragma unroll
  for (int cm = 0; cm < CTM; ++cm)
#pragma unroll
    for (int r = 0; r < 4; ++r) {
      float s = 0.f, q = 0.f;
#pragma unroll
      for (int pn = 0; pn < CTN; ++pn) {
        float v = acc[cm][pn][r];
        s += v;
        q = fmaf(v, v, q);
      }
#pragma unroll
      for (int mask = 1; mask < 16; mask <<= 1) {
        s += __shfl_xor(s, mask, 64);
        q += __shfl_xor(q, mask, 64);
      }
      sst[cm][r] = s;
      qst[cm][r] = q;
    }
  __syncthreads();
  float* sbuf = (float*)st;
  float* qbuf = sbuf + 8 * CTM * 16;
  if (l16 == 0) {
#pragma unroll
    for (int cm = 0; cm < CTM; ++cm)
#pragma unroll
      for (int r = 0; r < 4; ++r) {
        sbuf[((w * CTM + cm) * 4 + g) * 4 + r] = sst[cm][r];
        qbuf[((w * CTM + cm) * 4 + g) * 4 + r] = qst[cm][r];
      }
  }
  __syncthreads();
  if (tid < COB) {
    int wrow_t = tid / (CTM * 16);
    int rem = tid % (CTM * 16);
    float S = 0.f, Q = 0.f;
#pragma unroll
    for (int j = 0; j < WN; ++j) {
      int wvx = wrow_t * WN + j;
      S += sbuf[(wvx * CTM) * 16 + rem];
      Q += qbuf[(wvx * CTM) * 16 + rem];
    }
    const int blk = blockIdx.x * gridDim.y + blockIdx.y;
    const int nblk = 1024 * gridDim.y;
    size_t slot = ((size_t)(co_base + tid) * nblk + blk) * 2;
    part[slot] = (double)S;
    part[slot + 1] = (double)Q;
  }
}

// ---------------- BN scale/shift — parallel deterministic tree reduce -------
__global__ __launch_bounds__(256) void finalize_k(
    const double* __restrict__ part, int NB, const float* __restrict__ g,
    const float* __restrict__ bb, float* __restrict__ ss, int C, double invN) {
  __shared__ double sms[256], smq[256];
  const int c = blockIdx.x;
  const int t = threadIdx.x;
  double s = 0.0, q = 0.0;
  const double* base = part + (size_t)c * NB * 2;
  for (int i = t; i < NB; i += 256) {
    s += base[i * 2];
    q += base[i * 2 + 1];
  }
  sms[t] = s;
  smq[t] = q;
  __syncthreads();
  for (int st = 128; st; st >>= 1) {
    if (t < st) {
      sms[t] += sms[t + st];
      smq[t] += smq[t + st];
    }
    __syncthreads();
  }
  if (t == 0) {
    double mean = sms[0] * invN;
    double var = smq[0] * invN - mean * mean;
    float scale = g[c] * rsqrtf((float)var + 1e-5f);
    float shift = bb[c] - (float)mean * scale;
    ss[c] = scale;
    ss[C + c] = shift;
  }
}

// ---------------- L3: 1x1 conv from channel-last bf16 y3b + fused stats -----
__global__ __launch_bounds__(256) void conv1x1_k(
    const unsigned short* __restrict__ inT, const float* __restrict__ ss,
    const float* __restrict__ w, float* __restrict__ out,
    double* __restrict__ part) {
  __shared__ float sb1x[4][16], qb1x[4][16];
  const int b = blockIdx.x;
  const int co0 = blockIdx.y * 16;
  const int px = threadIdx.x;
  const int wv = threadIdx.x >> 6;
  float acc[16];
#pragma unroll
  for (int co = 0; co < 16; ++co) acc[co] = 0.f;
  const unsigned short* rowp = inT + ((size_t)b * 256 + px) * 64;
#pragma unroll
  for (int c8 = 0; c8 < 4; ++c8) {
    short8v raw = *(const short8v*)(rowp + c8 * 8);
#pragma unroll
    for (int e = 0; e < 8; ++e) {
      int c = c8 * 8 + e;
      float f = bf2f((unsigned short)raw[e]);
      f = fmaxf(fmaf(f, ss[c], ss[64 + c]), 0.f);
#pragma unroll
      for (int co = 0; co < 16; ++co)
        acc[co] = fmaf(f, w[(co0 + co) * 32 + c], acc[co]);
    }
  }
#pragma unroll
  for (int co = 0; co < 16; ++co)
    out[((size_t)b * 64 + co0 + co) * 256 + px] = acc[co];

#pragma unroll
  for (int co = 0; co < 16; ++co) {
    float s = wave_reduce(acc[co]);
    float q = wave_reduce(acc[co] * acc[co]);
    if ((threadIdx.x & 63) == 0) {
      sb1x[wv][co] = s;
      qb1x[wv][co] = q;
    }
  }
  __syncthreads();
  if (px < 16) {
    float S = 0.f, Q = 0.f;
#pragma unroll
    for (int k = 0; k < 4; ++k) {
      S += sb1x[k][px];
      Q += qb1x[k][px];
    }
    size_t slot = ((size_t)(co0 + px) * 1024 + b) * 2;
    part[slot] = (double)S;
    part[slot + 1] = (double)Q;
  }
}

// ---------------- convT + ALL losses (l1,l2,l3) ------------------------------
// A raw -> normalize (write back) ; S raw -> normalize (write back) + l2 fp32
// inline + Sb bf16 ; l3 from Sb rows ; convT via MFMA -> l1.
__global__ __launch_bounds__(256) void convt_l1_k(
    float* __restrict__ A, float* __restrict__ S, const float* __restrict__ x,
    const float* __restrict__ ssA, const float* __restrict__ ssS,
    double* __restrict__ l1p, double* __restrict__ l2p,
    double* __restrict__ l3p) {
  __shared__ unsigned short Ab[8][256][8];
  __shared__ unsigned short Sb[4][16][3][72];
  __shared__ float sbred[4], sbl2[4], sbl3[4];
  const int b = blockIdx.x, tid = threadIdx.x;
  const int w = tid >> 6, l = tid & 63;
  const int g = l >> 4, c = l & 15;
  const int pa = w >> 1, pb = w & 1;

  float* Ag = A + (size_t)b * 16384;
  for (int dp = 0; dp < 32; ++dp) {
    int d = dp * 2;
    float f0 = Ag[(size_t)d * 256 + tid];
    float f1 = Ag[(size_t)(d + 1) * 256 + tid];
    f0 = fmaxf(fmaf(f0, ssA[d], ssA[64 + d]), 0.f);
    f1 = fmaxf(fmaf(f1, ssA[d + 1], ssA[64 + d + 1]), 0.f);
    Ag[(size_t)d * 256 + tid] = f0;
    Ag[(size_t)(d + 1) * 256 + tid] = f1;
    unsigned lo = f2bf(f0);
    unsigned hi = f2bf(f1);
    *(unsigned*)&Ab[d >> 3][tid][d & 7] = lo | (hi << 16);
  }

  float* Sg = S + (size_t)b * 12288;
  float l2loc = 0.f;
  for (int i = tid; i < 12288; i += 256) {
    float raw = Sg[i];
    int cch = i >> 6;
    float f = fmaxf(fmaf(raw, ssS[cch], ssS[192 + cch]), 0.f);
    Sg[i] = f;      // normalized S to d_out
    l2loc += f;     // relu(f) == f
    int tap = i & 63;
    int d = cch / 3, t = cch - 3 * d;
    int ky = tap >> 3, kx = tap & 7;
    int par = (((ky & 1) ^ 1) << 1) | ((kx & 1) ^ 1);
    Sb[par][(ky >> 1) * 4 + (kx >> 1)][t][d] = f2bf(f);
  }
  __syncthreads();

  // l3 entropy: one (par,tap,t) row of 64 contiguous bf16 per thread (tid<192)
  float l3loc = 0.f;
  if (tid < 192) {
    int par = tid / 48, rr = tid - par * 48;
    int tap = rr / 3, t = rr - tap * 3;
    const unsigned short* rowp = &Sb[par][tap][t][0];
    short8v rv[8];
#pragma unroll
    for (int k = 0; k < 8; ++k) rv[k] = *(const short8v*)(rowp + k * 8);
    float m = -1e30f;
#pragma unroll
    for (int k = 0; k < 8; ++k)
#pragma unroll
      for (int e = 0; e < 8; ++e)
        m = fmaxf(m, bf2f((unsigned short)rv[k][e]));
    float Z = 0.f;
#pragma unroll
    for (int k = 0; k < 8; ++k)
#pragma unroll
      for (int e = 0; e < 8; ++e)
        Z += expf(bf2f((unsigned short)rv[k][e]) - m);
    float lZ = logf(Z);
#pragma unroll
    for (int k = 0; k < 8; ++k)
#pragma unroll
      for (int e = 0; e < 8; ++e) {
        float lp = bf2f((unsigned short)rv[k][e]) - m - lZ;
        l3loc = fmaf(expf(lp), lp, l3loc);
      }
  }

  f32x4 acc[16];
#pragma unroll
  for (int nt = 0; nt < 16; ++nt) {
    f32x4 z = {0.f, 0.f, 0.f, 0.f};
    acc[nt] = z;
  }

  const int shy = 1 + pa, shx = 1 + pb;
  for (int s = 0; s < 32; ++s) {
    const int tap = s >> 1;
    const int m = tap >> 2, n = tap & 3;
    const int dh = s & 1;
    short8v afr = {0, 0, 0, 0, 0, 0, 0, 0};
    if (c < 3) afr = *(const short8v*)&Sb[w][tap][c][dh * 32 + g * 8];
    const int ix = c + shx - n;
    const bool xok = (unsigned)ix < 16u;
    const int dblk = dh * 4 + g;
#pragma unroll
    for (int nt = 0; nt < 16; ++nt) {
      int iy = nt + shy - m;
      if ((unsigned)iy >= 16u) continue;
      short8v bfr = {0, 0, 0, 0, 0, 0, 0, 0};
      if (xok) bfr = *(const short8v*)&Ab[dblk][iy * 16 + ix][0];
      acc[nt] = __builtin_amdgcn_mfma_f32_16x16x32_bf16(afr, bfr, acc[nt],
                                                        0, 0, 0);
    }
  }

  float loc = 0.f;
  if (g == 0) {
    const float* xg = x + (size_t)b * 3072;
#pragma unroll
    for (int nt = 0; nt < 16; ++nt) {
      int oy = 2 * nt + pa, ox = 2 * c + pb;
#pragma unroll
      for (int r = 0; r < 3; ++r) {
        float recon = 1.f / (1.f + expf(-acc[nt][r]));
        float img = 1.f / (1.f + expf(-xg[r * 1024 + oy * 32 + ox]));
        float dd = img - recon;
        loc = fmaf(dd, dd, loc);
      }
    }
  }
  loc = wave_reduce(loc);
  l2loc = wave_reduce(l2loc);
  l3loc = wave_reduce(l3loc);
  if (l == 0) { sbred[w] = loc; sbl2[w] = l2loc; sbl3[w] = l3loc; }
  __syncthreads();
  if (tid == 0) {
    l1p[b] = (double)(sbred[0] + sbred[1] + sbred[2] + sbred[3]);
    l2p[b] = (double)(sbl2[0] + sbl2[1] + sbl2[2] + sbl2[3]);
    l3p[b] = (double)(sbl3[0] + sbl3[1] + sbl3[2] + sbl3[3]);
  }
}

// ---------------- deterministic final reduce of loss partials --------------
__global__ __launch_bounds__(256) void scalars_k(const double* __restrict__ l1p,
                                                 const double* __restrict__ l2p,
                                                 const double* __restrict__ l3p,
                                                 float* __restrict__ out) {
  __shared__ double sm[256];
  const int t = threadIdx.x;

  double a = 0.0;
  for (int i = t; i < 1024; i += 256) a += l1p[i];
  sm[t] = a;
  __syncthreads();
  for (int s = 128; s; s >>= 1) {
    if (t < s) sm[t] += sm[t + s];
    __syncthreads();
  }
  double L1 = sm[0];
  __syncthreads();

  a = 0.0;
  for (int i = t; i < 1024; i += 256) a += l2p[i];
  sm[t] = a;
  __syncthreads();
  for (int s = 128; s; s >>= 1) {
    if (t < s) sm[t] += sm[t + s];
    __syncthreads();
  }
  double L2 = sm[0];
  __syncthreads();

  a = 0.0;
  for (int i = t; i < 1024; i += 256) a += l3p[i];
  sm[t] = a;
  __syncthreads();
  for (int s = 128; s; s >>= 1) {
    if (t < s) sm[t] += sm[t + s];
    __syncthreads();
  }
  double L3 = sm[0];

  if (t == 0) {
    out[0] = (float)(0.1 * L1 / 3145728.0);
    out[1] = (float)(0.1 * L2 / 12582912.0);
    out[2] = (float)(-0.1 * L3 / 12582912.0);
  }
}

// ---------------------------------------------------------------------------
extern "C" void kernel_launch(void* const* d_in, const int* in_sizes, int n_in,
                              void* d_out, int out_size, void* d_ws,
                              size_t ws_size, hipStream_t stream) {
  const float* x = (const float*)d_in[0];
  const float* w1 = (const float*)d_in[1];
  const float* w2 = (const float*)d_in[2];
  const float* w3 = (const float*)d_in[3];
  const float* wa = (const float*)d_in[4];
  const float* ws1 = (const float*)d_in[5];
  const float* ws2 = (const float*)d_in[6];
  const float* gb[12];
  for (int i = 0; i < 12; ++i) gb[i] = (const float*)d_in[7 + i];

  float* dout = (float*)d_out;
  float* Aout = dout;                 // [1024,64,16,16]
  float* Sout = dout + 16777216LL;    // [1024,192,8,8]
  float* sc_out = dout + 29360128LL;  // 3 scalars

  // workspace layout (float offsets) — total ~343 MB
  float* wsf = (float*)d_ws;
  unsigned short* y1b = (unsigned short*)(wsf);              // 33.5M ush
  unsigned short* y2b = (unsigned short*)(wsf + 16777216LL); // 67.1M ush
  unsigned short* y3b = (unsigned short*)(wsf + 50331648LL); // 16.8M ush
  unsigned short* y5b = (unsigned short*)(wsf + 58720256LL); // 50.3M ush
  unsigned short* wts = (unsigned short*)(wsf + 83886080LL);
  unsigned short* w2r = wts;                 // 18,432
  unsigned short* w3r = wts + 18432;         // 36,864
  unsigned short* ws1r = wts + 55296;        // 55,296
  unsigned short* ws2r = wts + 110592;       // 331,776
  double* part = (double*)(wsf + 84107264LL);  // 786,432 dbl (max: L5)
  double* l1p = (double*)(wsf + 85680128LL);   // 1024
  double* l2p = l1p + 1024;                    // 1024
  double* l3p = l2p + 1024;                    // 1024
  float* ssL = (float*)(l3p + 1024);           // 6 x 384 floats
  float* ss0 = ssL, *ss1 = ssL + 384, *ss2 = ssL + 768;
  float* ss3 = ssL + 1152, *ss4 = ssL + 1536, *ss5 = ssL + 1920;

  // ---- weight reorders (single launch) ----
  wreord_all_k<<<1728, 256, 0, stream>>>(w2, w3, ws1, ws2, w2r, w3r, ws1r, ws2r);

  // ---- L0: conv1 3->32 (fp32) -> y1b bf16 channel-last, fused stats ----
  conv0_k<<<dim3(1024, 4), 256, 0, stream>>>(x, w1, y1b, part);
  finalize_k<<<32, 256, 0, stream>>>(part, 1024, gb[0], gb[1], ss0, 32, 1.0 / 1048576.0);

  // ---- L1: conv2 32->64 (GEMM, 1 phase) -> y2b ----
  convgemm_k<32, 0, 32, 1, 36, 64, 64, 32, 32, 1, 8, 2, 4, 2, 4, true>
      <<<dim3(1024, 4, 1), 512, 0, stream>>>(y1b, ss0, w2r, nullptr, y2b, part);
  finalize_k<<<64, 256, 0, stream>>>(part, 4096, gb[2], gb[3], ss1, 64, 1.0 / 1048576.0);

  // ---- L2: conv3 64->64 s2 (GEMM, 2 phases, 41.6KB LDS) -> y3b ----
  convgemm_k<64, 0, 64, 2, 36, 64, 64, 32, 16, 2, 8, 2, 4, 2, 2, true>
      <<<dim3(1024, 2, 1), 512, 0, stream>>>(y2b, ss1, w3r, nullptr, y3b, part);
  finalize_k<<<64, 256, 0, stream>>>(part, 2048, gb[4], gb[5], ss2, 64, 1.0 / 262144.0);

  // ---- L3: convA 1x1 (y3b ch 0..31) -> Aout fp32 raw, fused stats ----
  conv1x1_k<<<dim3(1024, 4), 256, 0, stream>>>(y3b, ss2, wa, Aout, part);
  finalize_k<<<64, 256, 0, stream>>>(part, 1024, gb[6], gb[7], ss3, 64, 1.0 / 262144.0);

  // ---- L4: convS1 32->192 (y3b ch 32..63, GEMM, z-split 2) -> y5b ----
  convgemm_k<64, 32, 32, 1, 36, 192, 96, 16, 16, 1, 16, 2, 4, 3, 4, true>
      <<<dim3(1024, 1, 2), 512, 0, stream>>>(y3b, ss2, ws1r, nullptr, y5b, part);
  finalize_k<<<192, 256, 0, stream>>>(part, 1024, gb[8], gb[9], ss4, 192, 1.0 / 262144.0);

  // ---- L5: convS2 192->192 s2 (GEMM, 3 phases, 22KB LDS) -> Sout raw ----
  convgemm_k<192, 0, 192, 3, 68, 192, 192, 16, 8, 2, 4, 4, 2, 3, 1, false>
      <<<dim3(1024, 2, 1), 512, 0, stream>>>(y5b, ss4, ws2r, Sout, nullptr, part);
  finalize_k<<<192, 256, 0, stream>>>(part, 2048, gb[10], gb[11], ss5, 192, 1.0 / 65536.0);

  // ---- convT + all losses (normalizes A and S in place) ----
  convt_l1_k<<<1024, 256, 0, stream>>>(Aout, Sout, x, ss3, ss5, l1p, l2p, l3p);
  scalars_k<<<1, 256, 0, stream>>>(l1p, l2p, l3p, sc_out);
}